// Round 8
// baseline (21.620 us; speedup 1.0000x reference)
//
#include <hip/hip_runtime.h>

namespace {
constexpr int kFrame = 80;     // FRAME_SIZE
constexpr int kRad   = 2;      // RADIUS
constexpr int kW     = 5;      // 2*RADIUS+1
constexpr int kB     = 64;
constexpr int kF     = 4000;
constexpr int kN     = kFrame * kF;        // 320000 samples per batch row

constexpr int FPB     = 64;                // frames per block (4 threads/frame)
constexpr int BPB     = (kF + FPB - 1) / FPB;  // 63 blocks per batch
constexpr int HALO_LO = 304;               // covers lbase >= 4 (p <= 298); mult of 16
constexpr int HALO_HI = 84;
constexpr int LN      = FPB * kFrame + HALO_LO + HALO_HI;   // 5508 logical floats
constexpr int LPHYS   = LN + 4 * ((LN + 31) / 32);          // 6200 floats (24.8 KB)
constexpr int NQ      = 6;   // staging quads per thread = ceil(LN/4/256)
}

// Bank-deconflict remap: +4 pad words per 32. Preserves contiguity AND 16B
// alignment of any aligned quad.
__device__ __forceinline__ int phys(int i) { return i + ((i >> 5) << 2); }

// Issue ALL global loads first (back-to-back, one vmcnt ramp), write LDS later.
template <bool SAFE>
__device__ __forceinline__ void issue_stage(const float* __restrict__ xb, int o,
                                            int tid, float4* r) {
#pragma unroll
    for (int k = 0; k < NQ; ++k) {
        int i4 = (k * 256 + tid) * 4;
        if (i4 < LN) {
            if constexpr (SAFE) {
                r[k] = *reinterpret_cast<const float4*>(xb + o + i4);
            } else {
                int g = o + i4;
                // JAX pad semantics: g<0 -> 0; g>=N -> x[N-1]
                float t0 = (g + 0 >= 0) ? xb[min(g + 0, kN - 1)] : 0.f;
                float t1 = (g + 1 >= 0) ? xb[min(g + 1, kN - 1)] : 0.f;
                float t2 = (g + 2 >= 0) ? xb[min(g + 2, kN - 1)] : 0.f;
                float t3 = (g + 3 >= 0) ? xb[min(g + 3, kN - 1)] : 0.f;
                r[k] = make_float4(t0, t1, t2, t3);
            }
        }
    }
}

__device__ __forceinline__ void write_stage(float* __restrict__ buf, int tid,
                                            const float4* r) {
#pragma unroll
    for (int k = 0; k < NQ; ++k) {
        int i4 = (k * 256 + tid) * 4;
        if (i4 < LN)
            *reinterpret_cast<float4*>(&buf[phys(i4)]) = r[k];
    }
}

// (256,6): cap 85 VGPR -> 6 blocks/CU (LDS allows 6). Scalarized compute's
// true peak demand ~60 VGPR, so no spill expected (R3's spill was the
// SROA-array interaction, not raw pressure). If WRITE_SIZE blows up: revert.
__global__ __launch_bounds__(256, 6)
void pitch_acorr_kernel(const float* __restrict__ x,
                        const int* __restrict__ periods,
                        float* __restrict__ out) {
    __shared__ float lds[LPHYS];

    const int bid = blockIdx.x;
    const int b   = bid / BPB;
    const int blk = bid - b * BPB;
    const int f0  = blk * FPB;
    const int nf  = min(FPB, kF - f0);
    const int tid = threadIdx.x;
    const int fl  = tid >> 2;     // local frame
    const int q   = tid & 3;      // quarter: samples [20q, 20q+20)
    const int h   = q * 20;
    const float* xb = x + (long long)b * kN;
    const int o = f0 * kFrame - HALO_LO;   // global idx of lds logical 0

    // Prefetch period; its latency hides under the staging loads.
    const int p = periods[b * kF + min(f0 + fl, kF - 1)];

    float4 r[NQ];
    const bool safe = (o >= 0) && (o + LN <= kN);   // block-uniform
    if (safe) issue_stage<true >(xb, o, tid, r);
    else      issue_stage<false>(xb, o, tid, r);
    write_stage(lds, tid, r);
    __syncthreads();

    if (fl >= nf) return;        // no barriers below

    const int fbase = fl * kFrame + HALO_LO;   // logical idx of frame start
    const int lbase = fbase - p - kRad;        // >= 4 always (p <= 298)
    const int s     = lbase & 3;               // quad misalignment, 0..3
    const int A0    = lbase - s;               // 16B-aligned lag base
    const int fst   = fbase + h;
    const int gst   = A0 + h;

#define LD4(i) (*reinterpret_cast<const float4*>(&lds[phys(i)]))
    const float4 Ga = LD4(gst +  0), Gb = LD4(gst +  4), Gc = LD4(gst +  8),
                 Gd = LD4(gst + 12), Ge = LD4(gst + 16), Gf = LD4(gst + 20),
                 Gg = LD4(gst + 24);

    const float g0 = Ga.x, g1 = Ga.y, g2 = Ga.z, g3 = Ga.w,
                g4 = Gb.x, g5 = Gb.y, g6 = Gb.z, g7 = Gb.w,
                g8 = Gc.x, g9 = Gc.y, g10 = Gc.z, g11 = Gc.w,
                g12 = Gd.x, g13 = Gd.y, g14 = Gd.z, g15 = Gd.w,
                g16 = Ge.x, g17 = Ge.y, g18 = Ge.z, g19 = Ge.w,
                g20 = Gf.x, g21 = Gf.y, g22 = Gf.z, g23 = Gf.w,
                g24 = Gg.x, g25 = Gg.y, g26 = Gg.z;

    const float E0 = g0*g0 + g1*g1 + g2*g2 + g3*g3 + g4*g4 + g5*g5 + g6*g6
                   + g7*g7 + g8*g8 + g9*g9 + g10*g10 + g11*g11 + g12*g12
                   + g13*g13 + g14*g14 + g15*g15 + g16*g16 + g17*g17 + g18*g18
                   + g19*g19;

    float fn = 0.f;
    float D0 = 0.f, D1 = 0.f, D2 = 0.f, D3 = 0.f,
          D4 = 0.f, D5 = 0.f, D6 = 0.f, D7 = 0.f;

#define STEP(FT, A, B, C, D, E, F, G, H)                                       \
    { const float ft = (FT);                                                   \
      fn += ft * ft;                                                           \
      D0 += ft * (A); D1 += ft * (B); D2 += ft * (C); D3 += ft * (D);          \
      D4 += ft * (E); D5 += ft * (F); D6 += ft * (G); D7 += ft * (H); }

    { const float4 Fa = LD4(fst + 0);
      STEP(Fa.x, g0, g1, g2, g3, g4, g5, g6, g7)
      STEP(Fa.y, g1, g2, g3, g4, g5, g6, g7, g8)
      STEP(Fa.z, g2, g3, g4, g5, g6, g7, g8, g9)
      STEP(Fa.w, g3, g4, g5, g6, g7, g8, g9, g10) }
    { const float4 Fb = LD4(fst + 4);
      STEP(Fb.x, g4, g5, g6, g7, g8, g9, g10, g11)
      STEP(Fb.y, g5, g6, g7, g8, g9, g10, g11, g12)
      STEP(Fb.z, g6, g7, g8, g9, g10, g11, g12, g13)
      STEP(Fb.w, g7, g8, g9, g10, g11, g12, g13, g14) }
    { const float4 Fc = LD4(fst + 8);
      STEP(Fc.x, g8, g9, g10, g11, g12, g13, g14, g15)
      STEP(Fc.y, g9, g10, g11, g12, g13, g14, g15, g16)
      STEP(Fc.z, g10, g11, g12, g13, g14, g15, g16, g17)
      STEP(Fc.w, g11, g12, g13, g14, g15, g16, g17, g18) }
    { const float4 Fd = LD4(fst + 12);
      STEP(Fd.x, g12, g13, g14, g15, g16, g17, g18, g19)
      STEP(Fd.y, g13, g14, g15, g16, g17, g18, g19, g20)
      STEP(Fd.z, g14, g15, g16, g17, g18, g19, g20, g21)
      STEP(Fd.w, g15, g16, g17, g18, g19, g20, g21, g22) }
    { const float4 Fe = LD4(fst + 16);
      STEP(Fe.x, g16, g17, g18, g19, g20, g21, g22, g23)
      STEP(Fe.y, g17, g18, g19, g20, g21, g22, g23, g24)
      STEP(Fe.z, g18, g19, g20, g21, g22, g23, g24, g25)
      STEP(Fe.w, g19, g20, g21, g22, g23, g24, g25, g26) }
#undef STEP
#undef LD4

    const float E1 = E0 + (g20*g20 - g0*g0);
    const float E2 = E1 + (g21*g21 - g1*g1);
    const float E3 = E2 + (g22*g22 - g2*g2);
    const float E4 = E3 + (g23*g23 - g3*g3);
    const float E5 = E4 + (g24*g24 - g4*g4);
    const float E6 = E5 + (g25*g25 - g5*g5);
    const float E7 = E6 + (g26*g26 - g6*g6);

    // d_k = D_{k+s}, e_k = E_{k+s}
    const bool s1 = (s & 1) != 0, s2 = (s & 2) != 0;
    float d0 = s2 ? (s1 ? D3 : D2) : (s1 ? D1 : D0);
    float d1 = s2 ? (s1 ? D4 : D3) : (s1 ? D2 : D1);
    float d2 = s2 ? (s1 ? D5 : D4) : (s1 ? D3 : D2);
    float d3 = s2 ? (s1 ? D6 : D5) : (s1 ? D4 : D3);
    float d4 = s2 ? (s1 ? D7 : D6) : (s1 ? D5 : D4);
    float e0 = s2 ? (s1 ? E3 : E2) : (s1 ? E1 : E0);
    float e1 = s2 ? (s1 ? E4 : E3) : (s1 ? E2 : E1);
    float e2 = s2 ? (s1 ? E5 : E4) : (s1 ? E3 : E2);
    float e3 = s2 ? (s1 ? E6 : E5) : (s1 ? E4 : E3);
    float e4 = s2 ? (s1 ? E7 : E6) : (s1 ? E5 : E4);

    // butterfly-reduce over the 4 quarter-threads of this frame
    fn += __shfl_xor(fn, 1); fn += __shfl_xor(fn, 2);
    d0 += __shfl_xor(d0, 1); d0 += __shfl_xor(d0, 2);
    d1 += __shfl_xor(d1, 1); d1 += __shfl_xor(d1, 2);
    d2 += __shfl_xor(d2, 1); d2 += __shfl_xor(d2, 2);
    d3 += __shfl_xor(d3, 1); d3 += __shfl_xor(d3, 2);
    d4 += __shfl_xor(d4, 1); d4 += __shfl_xor(d4, 2);
    e0 += __shfl_xor(e0, 1); e0 += __shfl_xor(e0, 2);
    e1 += __shfl_xor(e1, 1); e1 += __shfl_xor(e1, 2);
    e2 += __shfl_xor(e2, 1); e2 += __shfl_xor(e2, 2);
    e3 += __shfl_xor(e3, 1); e3 += __shfl_xor(e3, 2);
    e4 += __shfl_xor(e4, 1); e4 += __shfl_xor(e4, 2);

    // Distributed store: lane q writes op[q]; lane 0 also op[4].
    float* op = out + (long long)(b * kF + f0 + fl) * kW;
    const float dq = (q & 2) ? ((q & 1) ? d3 : d2) : ((q & 1) ? d1 : d0);
    const float eq = (q & 2) ? ((q & 1) ? e3 : e2) : ((q & 1) ? e1 : e0);
    op[q] = dq * rsqrtf(fn * eq + 1e-9f);
    if (q == 0) op[4] = d4 * rsqrtf(fn * e4 + 1e-9f);
}

extern "C" void kernel_launch(void* const* d_in, const int* in_sizes, int n_in,
                              void* d_out, int out_size, void* d_ws, size_t ws_size,
                              hipStream_t stream) {
    const float* x       = (const float*)d_in[0];
    const int*   periods = (const int*)d_in[1];
    float*       out     = (float*)d_out;

    const int grid = kB * BPB;   // 4032 blocks, one per (batch, 64-frame chunk)
    pitch_acorr_kernel<<<grid, 256, 0, stream>>>(x, periods, out);
}

// Round 9
// 20.899 us; speedup vs baseline: 1.0345x; 1.0345x over previous
//
#include <hip/hip_runtime.h>

namespace {
constexpr int kFrame = 80;     // FRAME_SIZE
constexpr int kRad   = 2;      // RADIUS
constexpr int kW     = 5;      // 2*RADIUS+1
constexpr int kB     = 64;
constexpr int kF     = 4000;
constexpr int kN     = kFrame * kF;        // 320000 samples per batch row

constexpr int FPB     = 64;                // frames per block (4 threads/frame)
constexpr int BPB     = (kF + FPB - 1) / FPB;  // 63 blocks per batch
constexpr int HALO_LO = 304;               // covers lbase >= 4 (p <= 298); mult of 16
constexpr int HALO_HI = 84;
constexpr int LN      = FPB * kFrame + HALO_LO + HALO_HI;   // 5508 logical floats
constexpr int LPHYS   = LN + 4 * ((LN + 31) / 32);          // 6200 floats (24.8 KB)
constexpr int NQ      = 6;   // staging quads per thread = ceil(LN/4/256)
}

// Bank-deconflict remap: +4 pad words per 32. Preserves contiguity AND 16B
// alignment of any aligned quad.
__device__ __forceinline__ int phys(int i) { return i + ((i >> 5) << 2); }

// Quad-sum on the VALU pipe (DPP quad_perm), replacing ds_swizzle shuffles.
// Same pairwise order as the old __shfl_xor(1)/(2) butterfly -> bit-identical.
__device__ __forceinline__ float qsum(float v) {
    v += __int_as_float(__builtin_amdgcn_mov_dpp(__float_as_int(v), 0xB1, 0xF, 0xF, true)); // xor 1
    v += __int_as_float(__builtin_amdgcn_mov_dpp(__float_as_int(v), 0x4E, 0xF, 0xF, true)); // xor 2
    return v;
}

// Issue ALL global staging loads first (back-to-back, one vmcnt ramp).
template <bool SAFE>
__device__ __forceinline__ void issue_stage(const float* __restrict__ xb, int o,
                                            int tid, float4* r) {
#pragma unroll
    for (int k = 0; k < NQ; ++k) {
        int i4 = (k * 256 + tid) * 4;
        if (i4 < LN) {
            if constexpr (SAFE) {
                r[k] = *reinterpret_cast<const float4*>(xb + o + i4);
            } else {
                int g = o + i4;
                // JAX pad semantics: g<0 -> 0; g>=N -> x[N-1]
                float t0 = (g + 0 >= 0) ? xb[min(g + 0, kN - 1)] : 0.f;
                float t1 = (g + 1 >= 0) ? xb[min(g + 1, kN - 1)] : 0.f;
                float t2 = (g + 2 >= 0) ? xb[min(g + 2, kN - 1)] : 0.f;
                float t3 = (g + 3 >= 0) ? xb[min(g + 3, kN - 1)] : 0.f;
                r[k] = make_float4(t0, t1, t2, t3);
            }
        }
    }
}

__device__ __forceinline__ void write_stage(float* __restrict__ buf, int tid,
                                            const float4* r) {
#pragma unroll
    for (int k = 0; k < NQ; ++k) {
        int i4 = (k * 256 + tid) * 4;
        if (i4 < LN)
            *reinterpret_cast<float4*>(&buf[phys(i4)]) = r[k];
    }
}

// (256,4): cap 128 VGPR (spill-safe; actual allocation ~75 decides occupancy,
// which R7/R8 showed is LDS-capped at 6 blocks/CU either way).
__global__ __launch_bounds__(256, 4)
void pitch_acorr_kernel(const float* __restrict__ x,
                        const int* __restrict__ periods,
                        float* __restrict__ out) {
    __shared__ float lds[LPHYS];

    const int bid = blockIdx.x;
    const int b   = bid / BPB;
    const int blk = bid - b * BPB;
    const int f0  = blk * FPB;
    const int nf  = min(FPB, kF - f0);
    const int tid = threadIdx.x;
    const int fl  = tid >> 2;     // local frame
    const int q   = tid & 3;      // quarter: samples [20q, 20q+20)
    const int h   = q * 20;
    const float* xb = x + (long long)b * kN;
    const int o = f0 * kFrame - HALO_LO;   // global idx of lds logical 0

    // Prefetch period; its latency hides under the staging loads.
    const int p = periods[b * kF + min(f0 + fl, kF - 1)];

    float4 r[NQ];
    const bool safe = (o >= 0) && (o + LN <= kN);   // block-uniform
    if (safe) issue_stage<true >(xb, o, tid, r);
    else      issue_stage<false>(xb, o, tid, r);

    // Frame samples: own 20 contiguous floats, direct from global (the staging
    // loads above pull these exact lines into L1/L2 -> absorbed re-read).
    // Clamp only triggers for tail-dead threads (fl >= nf); keeps VA in-bounds.
    const int frameg = (f0 + fl) * kFrame + h;
    float4 Fa, Fb, Fc, Fd, Fe;
    {
        const float* fb_ = xb;
        Fa = *reinterpret_cast<const float4*>(fb_ + min(frameg +  0, kN - 4));
        Fb = *reinterpret_cast<const float4*>(fb_ + min(frameg +  4, kN - 4));
        Fc = *reinterpret_cast<const float4*>(fb_ + min(frameg +  8, kN - 4));
        Fd = *reinterpret_cast<const float4*>(fb_ + min(frameg + 12, kN - 4));
        Fe = *reinterpret_cast<const float4*>(fb_ + min(frameg + 16, kN - 4));
    }

    write_stage(lds, tid, r);
    __syncthreads();

    if (fl >= nf) return;        // no barriers below

    const int fbase = fl * kFrame + HALO_LO;   // logical idx of frame start
    const int lbase = fbase - p - kRad;        // >= 4 always (p <= 298)
    const int s     = lbase & 3;               // quad misalignment, 0..3
    const int A0    = lbase - s;               // 16B-aligned lag base
    const int gst   = A0 + h;

#define LD4(i) (*reinterpret_cast<const float4*>(&lds[phys(i)]))
    const float4 Ga = LD4(gst +  0), Gb = LD4(gst +  4), Gc = LD4(gst +  8),
                 Gd = LD4(gst + 12), Ge = LD4(gst + 16), Gf = LD4(gst + 20),
                 Gg = LD4(gst + 24);
#undef LD4

    const float g0 = Ga.x, g1 = Ga.y, g2 = Ga.z, g3 = Ga.w,
                g4 = Gb.x, g5 = Gb.y, g6 = Gb.z, g7 = Gb.w,
                g8 = Gc.x, g9 = Gc.y, g10 = Gc.z, g11 = Gc.w,
                g12 = Gd.x, g13 = Gd.y, g14 = Gd.z, g15 = Gd.w,
                g16 = Ge.x, g17 = Ge.y, g18 = Ge.z, g19 = Ge.w,
                g20 = Gf.x, g21 = Gf.y, g22 = Gf.z, g23 = Gf.w,
                g24 = Gg.x, g25 = Gg.y, g26 = Gg.z;

    const float E0 = g0*g0 + g1*g1 + g2*g2 + g3*g3 + g4*g4 + g5*g5 + g6*g6
                   + g7*g7 + g8*g8 + g9*g9 + g10*g10 + g11*g11 + g12*g12
                   + g13*g13 + g14*g14 + g15*g15 + g16*g16 + g17*g17 + g18*g18
                   + g19*g19;

    float fn = 0.f;
    float D0 = 0.f, D1 = 0.f, D2 = 0.f, D3 = 0.f,
          D4 = 0.f, D5 = 0.f, D6 = 0.f, D7 = 0.f;

#define STEP(FT, A, B, C, D, E, F, G, H)                                       \
    { const float ft = (FT);                                                   \
      fn += ft * ft;                                                           \
      D0 += ft * (A); D1 += ft * (B); D2 += ft * (C); D3 += ft * (D);          \
      D4 += ft * (E); D5 += ft * (F); D6 += ft * (G); D7 += ft * (H); }

    STEP(Fa.x, g0, g1, g2, g3, g4, g5, g6, g7)
    STEP(Fa.y, g1, g2, g3, g4, g5, g6, g7, g8)
    STEP(Fa.z, g2, g3, g4, g5, g6, g7, g8, g9)
    STEP(Fa.w, g3, g4, g5, g6, g7, g8, g9, g10)
    STEP(Fb.x, g4, g5, g6, g7, g8, g9, g10, g11)
    STEP(Fb.y, g5, g6, g7, g8, g9, g10, g11, g12)
    STEP(Fb.z, g6, g7, g8, g9, g10, g11, g12, g13)
    STEP(Fb.w, g7, g8, g9, g10, g11, g12, g13, g14)
    STEP(Fc.x, g8, g9, g10, g11, g12, g13, g14, g15)
    STEP(Fc.y, g9, g10, g11, g12, g13, g14, g15, g16)
    STEP(Fc.z, g10, g11, g12, g13, g14, g15, g16, g17)
    STEP(Fc.w, g11, g12, g13, g14, g15, g16, g17, g18)
    STEP(Fd.x, g12, g13, g14, g15, g16, g17, g18, g19)
    STEP(Fd.y, g13, g14, g15, g16, g17, g18, g19, g20)
    STEP(Fd.z, g14, g15, g16, g17, g18, g19, g20, g21)
    STEP(Fd.w, g15, g16, g17, g18, g19, g20, g21, g22)
    STEP(Fe.x, g16, g17, g18, g19, g20, g21, g22, g23)
    STEP(Fe.y, g17, g18, g19, g20, g21, g22, g23, g24)
    STEP(Fe.z, g18, g19, g20, g21, g22, g23, g24, g25)
    STEP(Fe.w, g19, g20, g21, g22, g23, g24, g25, g26)
#undef STEP

    const float E1 = E0 + (g20*g20 - g0*g0);
    const float E2 = E1 + (g21*g21 - g1*g1);
    const float E3 = E2 + (g22*g22 - g2*g2);
    const float E4 = E3 + (g23*g23 - g3*g3);
    const float E5 = E4 + (g24*g24 - g4*g4);
    const float E6 = E5 + (g25*g25 - g5*g5);
    const float E7 = E6 + (g26*g26 - g6*g6);

    // d_k = D_{k+s}, e_k = E_{k+s}
    const bool s1 = (s & 1) != 0, s2 = (s & 2) != 0;
    float d0 = s2 ? (s1 ? D3 : D2) : (s1 ? D1 : D0);
    float d1 = s2 ? (s1 ? D4 : D3) : (s1 ? D2 : D1);
    float d2 = s2 ? (s1 ? D5 : D4) : (s1 ? D3 : D2);
    float d3 = s2 ? (s1 ? D6 : D5) : (s1 ? D4 : D3);
    float d4 = s2 ? (s1 ? D7 : D6) : (s1 ? D5 : D4);
    float e0 = s2 ? (s1 ? E3 : E2) : (s1 ? E1 : E0);
    float e1 = s2 ? (s1 ? E4 : E3) : (s1 ? E2 : E1);
    float e2 = s2 ? (s1 ? E5 : E4) : (s1 ? E3 : E2);
    float e3 = s2 ? (s1 ? E6 : E5) : (s1 ? E4 : E3);
    float e4 = s2 ? (s1 ? E7 : E6) : (s1 ? E5 : E4);

    // quad-reduce on VALU (DPP): all 4 lanes end with the full sums
    fn = qsum(fn);
    d0 = qsum(d0); d1 = qsum(d1); d2 = qsum(d2); d3 = qsum(d3); d4 = qsum(d4);
    e0 = qsum(e0); e1 = qsum(e1); e2 = qsum(e2); e3 = qsum(e3); e4 = qsum(e4);

    // Distributed store: lane q writes op[q]; lane 0 also op[4].
    float* op = out + (long long)(b * kF + f0 + fl) * kW;
    const float dq = (q & 2) ? ((q & 1) ? d3 : d2) : ((q & 1) ? d1 : d0);
    const float eq = (q & 2) ? ((q & 1) ? e3 : e2) : ((q & 1) ? e1 : e0);
    op[q] = dq * rsqrtf(fn * eq + 1e-9f);
    if (q == 0) op[4] = d4 * rsqrtf(fn * e4 + 1e-9f);
}

extern "C" void kernel_launch(void* const* d_in, const int* in_sizes, int n_in,
                              void* d_out, int out_size, void* d_ws, size_t ws_size,
                              hipStream_t stream) {
    const float* x       = (const float*)d_in[0];
    const int*   periods = (const int*)d_in[1];
    float*       out     = (float*)d_out;

    const int grid = kB * BPB;   // 4032 blocks, one per (batch, 64-frame chunk)
    pitch_acorr_kernel<<<grid, 256, 0, stream>>>(x, periods, out);
}

// Round 10
// 20.526 us; speedup vs baseline: 1.0533x; 1.0181x over previous
//
#include <hip/hip_runtime.h>

namespace {
constexpr int kFrame = 80;     // FRAME_SIZE
constexpr int kRad   = 2;      // RADIUS
constexpr int kW     = 5;      // 2*RADIUS+1
constexpr int kB     = 64;
constexpr int kF     = 4000;
constexpr int kN     = kFrame * kF;        // 320000 samples per batch row

constexpr int FPB   = 64;                  // frames per block (4 threads/frame)
constexpr int NBLK  = (kB * kF) / FPB;     // 4000 blocks (exact)
constexpr int NXCD  = 8;
constexpr int CPX   = NBLK / NXCD;         // 500 (NBLK%8==0 -> bijective swizzle)
}

// Quad-sum on the VALU pipe (DPP quad_perm) — same pairwise order as
// __shfl_xor(1)/(2), bit-identical result, no LDS-pipe traffic.
__device__ __forceinline__ float qsum(float v) {
    v += __int_as_float(__builtin_amdgcn_mov_dpp(__float_as_int(v), 0xB1, 0xF, 0xF, true)); // xor 1
    v += __int_as_float(__builtin_amdgcn_mov_dpp(__float_as_int(v), 0x4E, 0xF, 0xF, true)); // xor 2
    return v;
}

// JAX pad/clamp semantics for the rare edge frames: g<0 -> 0, g>=N -> x[N-1].
__device__ __forceinline__ float4 ld4c(const float* __restrict__ xb, int g) {
    float t0 = (g + 0 >= 0) ? xb[min(g + 0, kN - 1)] : 0.f;
    float t1 = (g + 1 >= 0) ? xb[min(g + 1, kN - 1)] : 0.f;
    float t2 = (g + 2 >= 0) ? xb[min(g + 2, kN - 1)] : 0.f;
    float t3 = (g + 3 >= 0) ? xb[min(g + 3, kN - 1)] : 0.f;
    return make_float4(t0, t1, t2, t3);
}

// No LDS, no barrier: waves are independent and drift out of phase, so VMEM
// latency of some waves overlaps VALU of others (R9 post-mortem: the LDS
// version was phase-locked, not pipe-bound). x is L3-resident; lag windows
// of adjacent frames are served by L1/L2.
__global__ __launch_bounds__(256, 4)
void pitch_acorr_kernel(const float* __restrict__ x,
                        const int* __restrict__ periods,
                        float* __restrict__ out) {
    const int bid = blockIdx.x;
    // XCD-chunked swizzle: hw blocks round-robin XCDs; give each XCD a
    // contiguous frame range so overlapping windows hit its private L2.
    const int wid = (bid & (NXCD - 1)) * CPX + (bid >> 3);
    const int tid = threadIdx.x;
    const int fl  = tid >> 2;     // local frame in block
    const int q   = tid & 3;      // quarter: samples [20q, 20q+20)
    const int h   = q * 20;

    const int gf = wid * FPB + fl;          // global frame id, exact range
    const int b  = gf / kF;                 // magic-mul division
    const int f  = gf - b * kF;
    const float* xb = x + (long long)b * kN;

    const int p = periods[gf];              // issue first (longest dep chain)

    // Frame samples: always in-bounds ([f*80, f*80+79]).
    const int fst = f * kFrame + h;
    const float4 Fa = *reinterpret_cast<const float4*>(xb + fst +  0);
    const float4 Fb = *reinterpret_cast<const float4*>(xb + fst +  4);
    const float4 Fc = *reinterpret_cast<const float4*>(xb + fst +  8);
    const float4 Fd = *reinterpret_cast<const float4*>(xb + fst + 12);
    const float4 Fe = *reinterpret_cast<const float4*>(xb + fst + 16);

    const int lbase = f * kFrame - p - kRad;   // may be negative (>= -301)
    const int s     = lbase & 3;               // two's complement: floor-mod, ok
    const int A0    = lbase - s;               // 16B-aligned lag base
    const int gst   = A0 + h;

    float4 Ga, Gb, Gc, Gd, Ge, Gf_, Gg;
    // Needs words [A0, A0+87]; unsafe only for f<4 (A0<0) or f=3999 & p<6.
    const bool safe = (A0 >= 0) && (A0 + 88 <= kN);
    if (safe) {
        Ga = *reinterpret_cast<const float4*>(xb + gst +  0);
        Gb = *reinterpret_cast<const float4*>(xb + gst +  4);
        Gc = *reinterpret_cast<const float4*>(xb + gst +  8);
        Gd = *reinterpret_cast<const float4*>(xb + gst + 12);
        Ge = *reinterpret_cast<const float4*>(xb + gst + 16);
        Gf_= *reinterpret_cast<const float4*>(xb + gst + 20);
        Gg = *reinterpret_cast<const float4*>(xb + gst + 24);
    } else {
        Ga = ld4c(xb, gst +  0);
        Gb = ld4c(xb, gst +  4);
        Gc = ld4c(xb, gst +  8);
        Gd = ld4c(xb, gst + 12);
        Ge = ld4c(xb, gst + 16);
        Gf_= ld4c(xb, gst + 20);
        Gg = ld4c(xb, gst + 24);
    }

    const float g0 = Ga.x, g1 = Ga.y, g2 = Ga.z, g3 = Ga.w,
                g4 = Gb.x, g5 = Gb.y, g6 = Gb.z, g7 = Gb.w,
                g8 = Gc.x, g9 = Gc.y, g10 = Gc.z, g11 = Gc.w,
                g12 = Gd.x, g13 = Gd.y, g14 = Gd.z, g15 = Gd.w,
                g16 = Ge.x, g17 = Ge.y, g18 = Ge.z, g19 = Ge.w,
                g20 = Gf_.x, g21 = Gf_.y, g22 = Gf_.z, g23 = Gf_.w,
                g24 = Gg.x, g25 = Gg.y, g26 = Gg.z;

    const float E0 = g0*g0 + g1*g1 + g2*g2 + g3*g3 + g4*g4 + g5*g5 + g6*g6
                   + g7*g7 + g8*g8 + g9*g9 + g10*g10 + g11*g11 + g12*g12
                   + g13*g13 + g14*g14 + g15*g15 + g16*g16 + g17*g17 + g18*g18
                   + g19*g19;

    float fn = 0.f;
    float D0 = 0.f, D1 = 0.f, D2 = 0.f, D3 = 0.f,
          D4 = 0.f, D5 = 0.f, D6 = 0.f, D7 = 0.f;

#define STEP(FT, A, B, C, D, E, F, G, H)                                       \
    { const float ft = (FT);                                                   \
      fn += ft * ft;                                                           \
      D0 += ft * (A); D1 += ft * (B); D2 += ft * (C); D3 += ft * (D);          \
      D4 += ft * (E); D5 += ft * (F); D6 += ft * (G); D7 += ft * (H); }

    STEP(Fa.x, g0, g1, g2, g3, g4, g5, g6, g7)
    STEP(Fa.y, g1, g2, g3, g4, g5, g6, g7, g8)
    STEP(Fa.z, g2, g3, g4, g5, g6, g7, g8, g9)
    STEP(Fa.w, g3, g4, g5, g6, g7, g8, g9, g10)
    STEP(Fb.x, g4, g5, g6, g7, g8, g9, g10, g11)
    STEP(Fb.y, g5, g6, g7, g8, g9, g10, g11, g12)
    STEP(Fb.z, g6, g7, g8, g9, g10, g11, g12, g13)
    STEP(Fb.w, g7, g8, g9, g10, g11, g12, g13, g14)
    STEP(Fc.x, g8, g9, g10, g11, g12, g13, g14, g15)
    STEP(Fc.y, g9, g10, g11, g12, g13, g14, g15, g16)
    STEP(Fc.z, g10, g11, g12, g13, g14, g15, g16, g17)
    STEP(Fc.w, g11, g12, g13, g14, g15, g16, g17, g18)
    STEP(Fd.x, g12, g13, g14, g15, g16, g17, g18, g19)
    STEP(Fd.y, g13, g14, g15, g16, g17, g18, g19, g20)
    STEP(Fd.z, g14, g15, g16, g17, g18, g19, g20, g21)
    STEP(Fd.w, g15, g16, g17, g18, g19, g20, g21, g22)
    STEP(Fe.x, g16, g17, g18, g19, g20, g21, g22, g23)
    STEP(Fe.y, g17, g18, g19, g20, g21, g22, g23, g24)
    STEP(Fe.z, g18, g19, g20, g21, g22, g23, g24, g25)
    STEP(Fe.w, g19, g20, g21, g22, g23, g24, g25, g26)
#undef STEP

    const float E1 = E0 + (g20*g20 - g0*g0);
    const float E2 = E1 + (g21*g21 - g1*g1);
    const float E3 = E2 + (g22*g22 - g2*g2);
    const float E4 = E3 + (g23*g23 - g3*g3);
    const float E5 = E4 + (g24*g24 - g4*g4);
    const float E6 = E5 + (g25*g25 - g5*g5);
    const float E7 = E6 + (g26*g26 - g6*g6);

    // d_k = D_{k+s}, e_k = E_{k+s}
    const bool s1 = (s & 1) != 0, s2 = (s & 2) != 0;
    float d0 = s2 ? (s1 ? D3 : D2) : (s1 ? D1 : D0);
    float d1 = s2 ? (s1 ? D4 : D3) : (s1 ? D2 : D1);
    float d2 = s2 ? (s1 ? D5 : D4) : (s1 ? D3 : D2);
    float d3 = s2 ? (s1 ? D6 : D5) : (s1 ? D4 : D3);
    float d4 = s2 ? (s1 ? D7 : D6) : (s1 ? D5 : D4);
    float e0 = s2 ? (s1 ? E3 : E2) : (s1 ? E1 : E0);
    float e1 = s2 ? (s1 ? E4 : E3) : (s1 ? E2 : E1);
    float e2 = s2 ? (s1 ? E5 : E4) : (s1 ? E3 : E2);
    float e3 = s2 ? (s1 ? E6 : E5) : (s1 ? E4 : E3);
    float e4 = s2 ? (s1 ? E7 : E6) : (s1 ? E5 : E4);

    // quad-reduce on VALU (DPP): all 4 lanes end with the full sums
    fn = qsum(fn);
    d0 = qsum(d0); d1 = qsum(d1); d2 = qsum(d2); d3 = qsum(d3); d4 = qsum(d4);
    e0 = qsum(e0); e1 = qsum(e1); e2 = qsum(e2); e3 = qsum(e3); e4 = qsum(e4);

    // Distributed store: lane q writes op[q]; lane 0 also op[4].
    float* op = out + (long long)gf * kW;
    const float dq = (q & 2) ? ((q & 1) ? d3 : d2) : ((q & 1) ? d1 : d0);
    const float eq = (q & 2) ? ((q & 1) ? e3 : e2) : ((q & 1) ? e1 : e0);
    op[q] = dq * rsqrtf(fn * eq + 1e-9f);
    if (q == 0) op[4] = d4 * rsqrtf(fn * e4 + 1e-9f);
}

extern "C" void kernel_launch(void* const* d_in, const int* in_sizes, int n_in,
                              void* d_out, int out_size, void* d_ws, size_t ws_size,
                              hipStream_t stream) {
    const float* x       = (const float*)d_in[0];
    const int*   periods = (const int*)d_in[1];
    float*       out     = (float*)d_out;

    pitch_acorr_kernel<<<NBLK, 256, 0, stream>>>(x, periods, out);
}

// Round 11
// 20.354 us; speedup vs baseline: 1.0622x; 1.0085x over previous
//
#include <hip/hip_runtime.h>

namespace {
constexpr int kFrame = 80;     // FRAME_SIZE
constexpr int kRad   = 2;      // RADIUS
constexpr int kW     = 5;      // 2*RADIUS+1
constexpr int kB     = 64;
constexpr int kF     = 4000;
constexpr int kN     = kFrame * kF;        // 320000 samples per batch row

constexpr int FPW  = 16;                   // frames per wave (slab unit); 4000%16==0
constexpr int WPB  = 4;                    // waves per block (independent slabs)
constexpr int NBLK = (kB * kF) / (FPW * WPB);   // 4000 blocks
constexpr int GPB  = kF / FPW;             // 250 wave-groups per batch

constexpr int HALO_LO = 320;               // multiple of 80, >= 302 (p<=298)
constexpr int HALO_HI = 84;
constexpr int LNW  = HALO_LO + FPW * kFrame + HALO_HI;  // 1684 logical floats
constexpr int SLAB = LNW + 4 * ((LNW + 79) / 80);       // 1772 floats (+4 pad/80)
constexpr int NQW  = (LNW / 4 + 63) / 64;  // 7 staging quads per lane

constexpr int NXCD = 8, CPX = NBLK / NXCD; // 500 (bijective swizzle)
}

// Row-padded LDS layout: float L lives at L + 4*(L/80). Row stride 84 floats
// -> F-read bank-group (5*fl+5q+u)%8 cycles all 8 groups = 2-way = free.
// Exact div-by-80 for L < 2048: (L>>4)/5 via magic 103>>9.
__device__ __forceinline__ int ldsPhys(int L) {
    int row = ((L >> 4) * 103) >> 9;
    return L + (row << 2);
}

// Quad-sum on VALU (DPP quad_perm) — bit-identical to __shfl_xor(1)/(2).
__device__ __forceinline__ float qsum(float v) {
    v += __int_as_float(__builtin_amdgcn_mov_dpp(__float_as_int(v), 0xB1, 0xF, 0xF, true)); // xor 1
    v += __int_as_float(__builtin_amdgcn_mov_dpp(__float_as_int(v), 0x4E, 0xF, 0xF, true)); // xor 2
    return v;
}

// Wave-private slab + zero barriers: intra-wave LDS ops complete in order,
// so ds_write -> ds_read within one wave needs no __syncthreads. Waves drift
// out of phase -> VMEM/LDS/VALU of different waves overlap (R7/R9 were
// phase-locked; R10 was TA-segment-bound at 80B lane stride).
__global__ __launch_bounds__(256, 4)
void pitch_acorr_kernel(const float* __restrict__ x,
                        const int* __restrict__ periods,
                        float* __restrict__ out) {
    __shared__ float lds[WPB * SLAB];   // 28.4 KB

    const int bid  = blockIdx.x;
    const int wid  = (bid & (NXCD - 1)) * CPX + (bid >> 3);   // XCD-chunked
    const int tid  = threadIdx.x;
    const int w    = tid >> 6;          // wave in block
    const int lane = tid & 63;
    const int fl   = lane >> 2;         // frame within wave (0..15)
    const int q    = lane & 3;          // quarter: samples [20q, 20q+20)
    const int h    = q * 20;
    float* __restrict__ slab = &lds[w * SLAB];

    const int ws = wid * WPB + w;       // global wave slot (0..15999)
    const int b  = ws / GPB;            // batch (compiler magic-div, exact)
    const int f0 = (ws - b * GPB) * FPW;       // first frame of slab in batch
    const float* xb = x + (long long)b * kN;
    const int o  = f0 * kFrame - HALO_LO;      // global idx of slab logical 0

    const int gf = ws * FPW + fl;       // global frame id == b*kF + f0 + fl
    const int p  = periods[gf];

    // ---- stage slab: 7 coalesced dwordx4 issued back-to-back ----
    float4 r[NQW];
    const bool safe = (o >= 0) && (o + LNW <= kN);   // wave-uniform
    if (safe) {
#pragma unroll
        for (int k = 0; k < NQW; ++k) {
            int i4 = (k * 64 + lane) * 4;
            if (i4 < LNW) r[k] = *reinterpret_cast<const float4*>(xb + o + i4);
        }
    } else {   // only first/last slab of each batch: JAX pad/clamp semantics
#pragma unroll
        for (int k = 0; k < NQW; ++k) {
            int i4 = (k * 64 + lane) * 4;
            if (i4 < LNW) {
                int g = o + i4;
                float t0 = (g + 0 >= 0) ? xb[min(g + 0, kN - 1)] : 0.f;
                float t1 = (g + 1 >= 0) ? xb[min(g + 1, kN - 1)] : 0.f;
                float t2 = (g + 2 >= 0) ? xb[min(g + 2, kN - 1)] : 0.f;
                float t3 = (g + 3 >= 0) ? xb[min(g + 3, kN - 1)] : 0.f;
                r[k] = make_float4(t0, t1, t2, t3);
            }
        }
    }
#pragma unroll
    for (int k = 0; k < NQW; ++k) {
        int i4 = (k * 64 + lane) * 4;
        if (i4 < LNW)
            *reinterpret_cast<float4*>(&slab[ldsPhys(i4)]) = r[k];
    }
    // no barrier — same-wave LDS pipe is in-order

    const int fbase = HALO_LO + fl * kFrame;   // logical frame start
    const int lbase = fbase - p - kRad;        // >= 20 always
    const int s     = lbase & 3;
    const int A0    = lbase - s;               // 16B-aligned lag base
    const int gst   = A0 + h;
    const int fst   = fbase + h;
    const int fph   = fst + ((4 + fl) << 2);   // fst + 4*(fst/80); all 5 F quads same row

    const float4 Fa = *reinterpret_cast<const float4*>(&slab[fph +  0]);
    const float4 Fb = *reinterpret_cast<const float4*>(&slab[fph +  4]);
    const float4 Fc = *reinterpret_cast<const float4*>(&slab[fph +  8]);
    const float4 Fd = *reinterpret_cast<const float4*>(&slab[fph + 12]);
    const float4 Fe = *reinterpret_cast<const float4*>(&slab[fph + 16]);

#define GQ(u) (*reinterpret_cast<const float4*>(&slab[ldsPhys(gst + 4 * (u))]))
    const float4 Ga = GQ(0), Gb = GQ(1), Gc = GQ(2), Gd = GQ(3),
                 Ge = GQ(4), Gf_ = GQ(5), Gg = GQ(6);
#undef GQ

    const float g0 = Ga.x, g1 = Ga.y, g2 = Ga.z, g3 = Ga.w,
                g4 = Gb.x, g5 = Gb.y, g6 = Gb.z, g7 = Gb.w,
                g8 = Gc.x, g9 = Gc.y, g10 = Gc.z, g11 = Gc.w,
                g12 = Gd.x, g13 = Gd.y, g14 = Gd.z, g15 = Gd.w,
                g16 = Ge.x, g17 = Ge.y, g18 = Ge.z, g19 = Ge.w,
                g20 = Gf_.x, g21 = Gf_.y, g22 = Gf_.z, g23 = Gf_.w,
                g24 = Gg.x, g25 = Gg.y, g26 = Gg.z;

    const float E0 = g0*g0 + g1*g1 + g2*g2 + g3*g3 + g4*g4 + g5*g5 + g6*g6
                   + g7*g7 + g8*g8 + g9*g9 + g10*g10 + g11*g11 + g12*g12
                   + g13*g13 + g14*g14 + g15*g15 + g16*g16 + g17*g17 + g18*g18
                   + g19*g19;

    float fn = 0.f;
    float D0 = 0.f, D1 = 0.f, D2 = 0.f, D3 = 0.f,
          D4 = 0.f, D5 = 0.f, D6 = 0.f, D7 = 0.f;

#define STEP(FT, A, B, C, D, E, F, G, H)                                       \
    { const float ft = (FT);                                                   \
      fn += ft * ft;                                                           \
      D0 += ft * (A); D1 += ft * (B); D2 += ft * (C); D3 += ft * (D);          \
      D4 += ft * (E); D5 += ft * (F); D6 += ft * (G); D7 += ft * (H); }

    STEP(Fa.x, g0, g1, g2, g3, g4, g5, g6, g7)
    STEP(Fa.y, g1, g2, g3, g4, g5, g6, g7, g8)
    STEP(Fa.z, g2, g3, g4, g5, g6, g7, g8, g9)
    STEP(Fa.w, g3, g4, g5, g6, g7, g8, g9, g10)
    STEP(Fb.x, g4, g5, g6, g7, g8, g9, g10, g11)
    STEP(Fb.y, g5, g6, g7, g8, g9, g10, g11, g12)
    STEP(Fb.z, g6, g7, g8, g9, g10, g11, g12, g13)
    STEP(Fb.w, g7, g8, g9, g10, g11, g12, g13, g14)
    STEP(Fc.x, g8, g9, g10, g11, g12, g13, g14, g15)
    STEP(Fc.y, g9, g10, g11, g12, g13, g14, g15, g16)
    STEP(Fc.z, g10, g11, g12, g13, g14, g15, g16, g17)
    STEP(Fc.w, g11, g12, g13, g14, g15, g16, g17, g18)
    STEP(Fd.x, g12, g13, g14, g15, g16, g17, g18, g19)
    STEP(Fd.y, g13, g14, g15, g16, g17, g18, g19, g20)
    STEP(Fd.z, g14, g15, g16, g17, g18, g19, g20, g21)
    STEP(Fd.w, g15, g16, g17, g18, g19, g20, g21, g22)
    STEP(Fe.x, g16, g17, g18, g19, g20, g21, g22, g23)
    STEP(Fe.y, g17, g18, g19, g20, g21, g22, g23, g24)
    STEP(Fe.z, g18, g19, g20, g21, g22, g23, g24, g25)
    STEP(Fe.w, g19, g20, g21, g22, g23, g24, g25, g26)
#undef STEP

    const float E1 = E0 + (g20*g20 - g0*g0);
    const float E2 = E1 + (g21*g21 - g1*g1);
    const float E3 = E2 + (g22*g22 - g2*g2);
    const float E4 = E3 + (g23*g23 - g3*g3);
    const float E5 = E4 + (g24*g24 - g4*g4);
    const float E6 = E5 + (g25*g25 - g5*g5);
    const float E7 = E6 + (g26*g26 - g6*g6);

    // d_k = D_{k+s}, e_k = E_{k+s}
    const bool s1 = (s & 1) != 0, s2 = (s & 2) != 0;
    float d0 = s2 ? (s1 ? D3 : D2) : (s1 ? D1 : D0);
    float d1 = s2 ? (s1 ? D4 : D3) : (s1 ? D2 : D1);
    float d2 = s2 ? (s1 ? D5 : D4) : (s1 ? D3 : D2);
    float d3 = s2 ? (s1 ? D6 : D5) : (s1 ? D4 : D3);
    float d4 = s2 ? (s1 ? D7 : D6) : (s1 ? D5 : D4);
    float e0 = s2 ? (s1 ? E3 : E2) : (s1 ? E1 : E0);
    float e1 = s2 ? (s1 ? E4 : E3) : (s1 ? E2 : E1);
    float e2 = s2 ? (s1 ? E5 : E4) : (s1 ? E3 : E2);
    float e3 = s2 ? (s1 ? E6 : E5) : (s1 ? E4 : E3);
    float e4 = s2 ? (s1 ? E7 : E6) : (s1 ? E5 : E4);

    // quad-reduce on VALU (DPP): all 4 lanes end with the full sums
    fn = qsum(fn);
    d0 = qsum(d0); d1 = qsum(d1); d2 = qsum(d2); d3 = qsum(d3); d4 = qsum(d4);
    e0 = qsum(e0); e1 = qsum(e1); e2 = qsum(e2); e3 = qsum(e3); e4 = qsum(e4);

    // Distributed store: lane q writes op[q]; lane 0 also op[4].
    float* op = out + (long long)gf * kW;
    const float dq = (q & 2) ? ((q & 1) ? d3 : d2) : ((q & 1) ? d1 : d0);
    const float eq = (q & 2) ? ((q & 1) ? e3 : e2) : ((q & 1) ? e1 : e0);
    op[q] = dq * rsqrtf(fn * eq + 1e-9f);
    if (q == 0) op[4] = d4 * rsqrtf(fn * e4 + 1e-9f);
}

extern "C" void kernel_launch(void* const* d_in, const int* in_sizes, int n_in,
                              void* d_out, int out_size, void* d_ws, size_t ws_size,
                              hipStream_t stream) {
    const float* x       = (const float*)d_in[0];
    const int*   periods = (const int*)d_in[1];
    float*       out     = (float*)d_out;

    pitch_acorr_kernel<<<NBLK, 256, 0, stream>>>(x, periods, out);
}